// Round 4
// baseline (590.935 us; speedup 1.0000x reference)
//
#include <hip/hip_runtime.h>

#define K_TAGS 50
#define T_MAX 256
#define START_TAG 48
#define END_TAG 49
#define LOG2E 1.4426950408889634f
#define LN2 0.6931471805599453f
#define KK 2500        // dwords per 50x50 step matrix
#define CH_LAST 2244   // last DMA chunk base (dwords): (10000B - 1024B)/4

// hardware transcendentals: v_exp_f32 is 2^x, v_log_f32 is log2(x)
#define EXP2F(x) __builtin_amdgcn_exp2f(x)
#define LOG2F(x) __builtin_amdgcn_logf(x)

// Barrier draining ONLY lgkmcnt: LDS ops visible, global DMA stays in flight.
#define LDS_BARRIER() __asm__ volatile("s_waitcnt lgkmcnt(0)\n\ts_barrier" ::: "memory")
// Fine-grained DMA gate: at most the 2 just-issued staging loads outstanding.
#define WAIT_VM2()    __asm__ volatile("s_waitcnt vmcnt(2)" ::: "memory")

typedef const __attribute__((address_space(1))) void* gas_t;
typedef __attribute__((address_space(3))) void* las_t;

// One global_load_lds_dwordx4: 64 lanes x 16B. g_src is per-lane (base+lane*4
// dwords); lds_dst is wave-uniform (HW adds lane*16B).
__device__ __forceinline__ void stage16(float* lds_dst, const float* g_src) {
    __builtin_amdgcn_global_load_lds((gas_t)g_src, (las_t)lds_dst, 16, 0, 0);
}

// One block per batch element; 512 threads = 8 waves.
// Scaled forward algorithm, linear domain: L[j] = 2^(beta[j]-M).
// Waves 0-4 DMA-stage step e+3 into sbuf[(e+3)%4] each epoch (2 chunks each,
// 10KB total); manual vmcnt(2) + one lgkm-only barrier per step publishes
// buffers two epochs ahead of their read -> no global latency on the chain.
// Chain per step: 8 uniform ds_read broadcasts of L -> mul tree -> ds_add_f32
// -> lgkm drain -> s_barrier. Next-step P = exp2(s*log2e) computed off-chain.
__global__ __launch_bounds__(512, 1) void crf_fwd_kernel(
    const float* __restrict__ scores, const int* __restrict__ targets,
    const int* __restrict__ lengths, float* __restrict__ accum)
{
    const int b    = blockIdx.x;
    const int tid  = threadIdx.x;
    const int wave = tid >> 6;
    const int lane = tid & 63;
    const int len  = lengths[b];
    const float* __restrict__ sp = scores + (size_t)b * T_MAX * KK;

    __shared__ float sbuf[4][KK];   // 40 KB score staging
    __shared__ float csum[4][64];   // rotating column-sum buffers

    // ---- prologue DMA: stage steps 1..3 into sbuf[1..3] (waves 0-4, 2 chunks each)
    if (wave < 5) {
        #pragma unroll
        for (int s = 1; s <= 3; ++s) {
            int tc = (s < len) ? s : (len - 1);
            const float* g0 = sp + (size_t)tc * KK;
            int b0 = 2 * wave * 256; if (b0 > CH_LAST) b0 = CH_LAST;
            int b1 = b0 + 256;       if (b1 > CH_LAST) b1 = CH_LAST;
            stage16(&sbuf[s][b0], g0 + b0 + lane * 4);
            stage16(&sbuf[s][b1], g0 + b1 + lane * 4);
        }
    }

    // ---- gold score (threads 0..255 handle t = tid) ----
    if (tid < T_MAX) {
        float g = 0.f;
        if (tid < len) {
            int tg = targets[b * T_MAX + tid];
            g = sp[(size_t)tid * KK + tg];
        }
        #pragma unroll
        for (int off = 32; off > 0; off >>= 1) g += __shfl_down(g, off, 64);
        if (lane == 0) atomicAdd(&accum[1], g);
    }

    // ---- init L0 (log2 domain start: bcur[j] = s[0][START][j]*log2e)
    const int lanec = (lane < K_TAGS) ? lane : (K_TAGS - 1);
    float bcur = sp[START_TAG * K_TAGS + lanec] * LOG2E;
    float M = __shfl(bcur, 0, 64);
    if (wave == 0)      csum[0][lane] = (lane < K_TAGS) ? EXP2F(bcur - M) : 0.f;
    else if (wave == 1) csum[1][lane] = 0.f;

    int rows[7];
    #pragma unroll
    for (int k = 0; k < 7; ++k) rows[k] = wave + 8 * k;  // rows[6] may be >= 50

    // one-time full drain: prologue DMA + init writes visible everywhere
    __asm__ volatile("s_waitcnt vmcnt(0) lgkmcnt(0)\n\ts_barrier" ::: "memory");

    // P for step 1 from sbuf[1]
    float P[7];
    #pragma unroll
    for (int k = 0; k < 7; ++k) {
        int i = rows[k];
        P[k] = EXP2F(sbuf[1][(i < K_TAGS ? i : 0) * K_TAGS + lanec] * LOG2E);
    }

    // Epoch e: step e. ADD=e%4, RD=(e+3)%4, ZR=(e+1)%4; BP=(e+1)%4 (next P),
    // BS=(e+3)%4 (stage target, step e+3).
    auto epoch = [&](int e, int ADD, int RD, int ZR, int BP, int BS) {
        // ---- critical chain: uniform broadcast reads of merged L_{e-1}
        float l0 = csum[RD][0];
        float Lk[7];
        #pragma unroll
        for (int k = 0; k < 7; ++k) {
            int i = rows[k];
            float v = csum[RD][(i < K_TAGS) ? i : 0];
            Lk[k] = (i < K_TAGS) ? v : 0.f;
        }
        int   ei    = (__float_as_int(l0) >> 23) & 0xFF;   // biased exponent of L[0]
        float scale = __int_as_float((254 - ei) << 23);    // 2^-(ei-127)
        float m0 = P[0]*Lk[0], m1 = P[1]*Lk[1], m2 = P[2]*Lk[2], m3 = P[3]*Lk[3],
              m4 = P[4]*Lk[4], m5 = P[5]*Lk[5], m6 = P[6]*Lk[6];
        float a = (((m0 + m1) + (m2 + m3)) + ((m4 + m5) + m6)) * scale;
        atomicAdd(&csum[ADD][lane], a);              // ds_add_f32 partial merge
        if (wave == 0) csum[ZR][lane] = 0.f;         // prep epoch e+1's ADD buffer
        M += (float)(ei - 127);

        // ---- off-chain: P for step e+1 (buffer guaranteed since last barrier)
        float Pn[7];
        #pragma unroll
        for (int k = 0; k < 7; ++k) {
            int i = rows[k];
            Pn[k] = EXP2F(sbuf[BP][(i < K_TAGS ? i : 0) * K_TAGS + lanec] * LOG2E);
        }

        // ---- DMA-stage step e+3 into sbuf[BS]
        int tc = e + 3; if (tc >= len) tc = len - 1;
        if (wave < 5) {
            const float* g0 = sp + (size_t)tc * KK;
            int b0 = 2 * wave * 256; if (b0 > CH_LAST) b0 = CH_LAST;
            int b1 = b0 + 256;       if (b1 > CH_LAST) b1 = CH_LAST;
            stage16(&sbuf[BS][b0], g0 + b0 + lane * 4);
            stage16(&sbuf[BS][b1], g0 + b1 + lane * 4);
        }
        WAIT_VM2();      // all but the 2 just-issued done => step e+2 landed
        LDS_BARRIER();   // publish; global DMA for e+3 stays in flight
        #pragma unroll
        for (int k = 0; k < 7; ++k) P[k] = Pn[k];
    };

    int t = 1;
    while (t < len) {
        epoch(t, 1, 0, 2, 2, 0); if (++t >= len) break;   // t%4==1
        epoch(t, 2, 1, 3, 3, 1); if (++t >= len) break;   // t%4==2
        epoch(t, 3, 2, 0, 0, 2); if (++t >= len) break;   // t%4==3
        epoch(t, 0, 3, 1, 1, 3); ++t;                     // t%4==0
    }

    float beta_end_log2;
    if (len >= 2) beta_end_log2 = M + LOG2F(csum[(len - 1) & 3][lane]);
    else          beta_end_log2 = bcur;
    if (tid == END_TAG)                       // wave 0, lane 49 = beta_final[END]
        atomicAdd(&accum[0], beta_end_log2 * LN2);
}

__global__ void finalize_kernel(const float* __restrict__ accum,
                                float* __restrict__ out, float invB)
{
    out[0] = (accum[0] - accum[1]) * invB;
}

extern "C" void kernel_launch(void* const* d_in, const int* in_sizes, int n_in,
                              void* d_out, int out_size, void* d_ws, size_t ws_size,
                              hipStream_t stream)
{
    const float* scores  = (const float*)d_in[0];
    const int*   targets = (const int*)d_in[1];
    const int*   lengths = (const int*)d_in[2];
    const int B = in_sizes[2];

    float* accum = (float*)d_ws;
    hipMemsetAsync(accum, 0, 2 * sizeof(float), stream);
    crf_fwd_kernel<<<B, 512, 0, stream>>>(scores, targets, lengths, accum);
    finalize_kernel<<<1, 1, 0, stream>>>(accum, (float*)d_out, 1.0f / (float)B);
}

// Round 5
// 535.679 us; speedup vs baseline: 1.1032x; 1.1032x over previous
//
#include <hip/hip_runtime.h>

#define K_TAGS 50
#define T_MAX 256
#define START_TAG 48
#define END_TAG 49
#define LOG2E 1.4426950408889634f
#define LN2 0.6931471805599453f
#define KK 2500   // dwords per 50x50 step matrix

// hardware transcendentals: v_exp_f32 is 2^x, v_log_f32 is log2(x)
#define EXP2F(x) __builtin_amdgcn_exp2f(x)
#define LOG2F(x) __builtin_amdgcn_logf(x)

__device__ __forceinline__ float rdlane(float v, int i) {
    return __int_as_float(__builtin_amdgcn_readlane(__float_as_int(v), i));
}

// ONE WAVE PER BATCH ELEMENT. Lane j owns tag/column j (lanes 50-63 duplicate
// column 49, results never read). Scaled forward algorithm in linear domain:
//   invariant: true log2-beta_t[j] = M + log2(L[j])
//   L_new[j]  = 2^-E0 * sum_i P[i][j] * L[i],  P = 2^(s*log2e) = e^s,  M += E0
// E0 = floor-exponent of L[0] (bit extract). No LDS, no barriers, no cross-wave
// traffic: the per-step chain is 50 readlane-broadcast FMAs into 5 accumulators.
// Scores for step t+2 are loaded (50 dword loads, ~200B coalesced each) while
// step t computes; P for step t+1 is exp'd from last iteration's loads.
// sched_barrier(0) after each load block stops the compiler sinking the loads
// to their use site (the round-3 failure).
__global__ __launch_bounds__(64, 1) void crf_fwd_kernel(
    const float* __restrict__ scores, const int* __restrict__ targets,
    const int* __restrict__ lengths, float* __restrict__ accum)
{
    const int b    = blockIdx.x;
    const int lane = threadIdx.x;
    const int len  = lengths[b];
    const float* __restrict__ sp = scores + (size_t)b * T_MAX * KK;
    const int j = (lane < K_TAGS) ? lane : (K_TAGS - 1);

    // ---- gold score (fused): 4 timesteps per lane, wave-reduce, one atomic ----
    {
        float g = 0.f;
        #pragma unroll
        for (int q = 0; q < 4; ++q) {
            int t = lane + 64 * q;
            if (t < len) {
                int tg = targets[b * T_MAX + t];
                g += sp[(size_t)t * KK + tg];
            }
        }
        #pragma unroll
        for (int off = 32; off; off >>= 1) g += __shfl_down(g, off, 64);
        if (lane == 0) atomicAdd(&accum[1], g);
    }

    // ---- init: log2-domain beta0, normalize into linear L ----
    float bcur = sp[START_TAG * K_TAGS + j] * LOG2E;
    float M = rdlane(bcur, 0);
    float L = EXP2F(bcur - M);

    float S0[50], S1[50], P0[50], P1[50];

    // column load: lane j grabs s[tc][i][j] for all 50 rows (stride 200 B)
    auto loadcol = [&](float (&dst)[50], int t) {
        int tc = (t < len) ? t : (len - 1);
        const float* s = sp + (size_t)tc * KK + j;
        #pragma unroll
        for (int i = 0; i < 50; ++i) dst[i] = s[i * K_TAGS];
    };

    // one step: L_new = scale * sum_i Pc[i] * broadcast(L, i)
    auto step_fn = [&](const float (&Pc)[50]) {
        float l0 = rdlane(L, 0);
        int   ei = (__float_as_int(l0) >> 23) & 0xFF;        // biased exponent
        float scale = __int_as_float((254 - ei) << 23);      // 2^-(ei-127)
        float a0 = 0.f, a1 = 0.f, a2 = 0.f, a3 = 0.f, a4 = 0.f;
        #pragma unroll
        for (int i = 0; i < 50; i += 5) {
            a0 = __builtin_fmaf(Pc[i + 0], rdlane(L, i + 0), a0);
            a1 = __builtin_fmaf(Pc[i + 1], rdlane(L, i + 1), a1);
            a2 = __builtin_fmaf(Pc[i + 2], rdlane(L, i + 2), a2);
            a3 = __builtin_fmaf(Pc[i + 3], rdlane(L, i + 3), a3);
            a4 = __builtin_fmaf(Pc[i + 4], rdlane(L, i + 4), a4);
        }
        L = (((a0 + a1) + (a2 + a3)) + a4) * scale;
        M += (float)(ei - 127);
    };

    // prologue: S(1)->S1, S(2)->S0, P(1)=exp(S1)
    loadcol(S1, 1);
    loadcol(S0, 2);
    __builtin_amdgcn_sched_barrier(0);
    #pragma unroll
    for (int i = 0; i < 50; ++i) P1[i] = EXP2F(S1[i] * LOG2E);

    // steady state: step s scores live in set (s&1); P(s) in P-set (s&1).
    int t = 1;
    while (t < len) {
        // t odd: consume P1(=P(t)); exp S0 -> P0(=P(t+1)); load S(t+2) -> S1
        loadcol(S1, t + 2);
        __builtin_amdgcn_sched_barrier(0);
        #pragma unroll
        for (int i = 0; i < 50; ++i) P0[i] = EXP2F(S0[i] * LOG2E);
        step_fn(P1);
        if (++t >= len) break;

        // t even: consume P0; exp S1 -> P1; load S(t+2) -> S0
        loadcol(S0, t + 2);
        __builtin_amdgcn_sched_barrier(0);
        #pragma unroll
        for (int i = 0; i < 50; ++i) P1[i] = EXP2F(S1[i] * LOG2E);
        step_fn(P0);
        ++t;
    }

    float beta_end = (len >= 2) ? (M + LOG2F(L)) : bcur;
    if (lane == END_TAG)                        // lane 49 holds beta_final[END]
        atomicAdd(&accum[0], beta_end * LN2);   // back to natural log
}

__global__ void finalize_kernel(const float* __restrict__ accum,
                                float* __restrict__ out, float invB)
{
    out[0] = (accum[0] - accum[1]) * invB;
}

extern "C" void kernel_launch(void* const* d_in, const int* in_sizes, int n_in,
                              void* d_out, int out_size, void* d_ws, size_t ws_size,
                              hipStream_t stream)
{
    const float* scores  = (const float*)d_in[0];
    const int*   targets = (const int*)d_in[1];
    const int*   lengths = (const int*)d_in[2];
    const int B = in_sizes[2];

    float* accum = (float*)d_ws;
    hipMemsetAsync(accum, 0, 2 * sizeof(float), stream);
    crf_fwd_kernel<<<B, 64, 0, stream>>>(scores, targets, lengths, accum);
    finalize_kernel<<<1, 1, 0, stream>>>(accum, (float*)d_out, 1.0f / (float)B);
}